// Round 1
// baseline (366.473 us; speedup 1.0000x reference)
//
#include <hip/hip_runtime.h>
#include <math.h>

// GRU cell with per-position weights.
// B=16, N=207, C=64, H=64. 3312 positions; each has its own Wx(64x192), Wh(64x192).
// Memory-bound: Wx+Wh = 325.6 MB read once -> ~52us roofline @ 6.3 TB/s.

#define GC 64    // input channels
#define GH 64    // hidden
#define J3 192   // 3*H

__global__ __launch_bounds__(192) void gru_cell_kernel(
    const float* __restrict__ x,      // (P, 64)
    const float* __restrict__ state,  // (P, 64)
    const float* __restrict__ Wx,     // (P, 64, 192)
    const float* __restrict__ Wh,     // (P, 64, 192)
    const float* __restrict__ b,      // (P, 192)
    float* __restrict__ out)          // (P, 64)
{
    const int pos = blockIdx.x;
    const int j = threadIdx.x;  // 0..191 : column of the 192-wide GEMV

    __shared__ float x_s[GC];
    __shared__ float h_s[GH];
    __shared__ float wch_s[GC][GH];   // staged Wch slice, 16 KB
    __shared__ float rh_s[GH];
    __shared__ float z_s[GH];

    const size_t wbase = (size_t)pos * GC * J3;
    const float* Wxp = Wx + wbase;
    const float* Whp = Wh + wbase;

    if (j < GC)           x_s[j]      = x[(size_t)pos * GC + j];
    else if (j < GC + GH) h_s[j - GC] = state[(size_t)pos * GH + (j - GC)];
    __syncthreads();

    // Pass 1: stream both weight matrices once (coalesced along j).
    // Wave 0 (j<64) and wave 1 (64<=j<128): accumulate x.Wx and h.W{r,z}.
    // Wave 2 (j>=128): accumulate x.Wxc and stage Wch into LDS.
    float accx = 0.f, acch = 0.f;
    const bool is_c = (j >= 128);       // wave-uniform
    const int jc = j - 128;
    #pragma unroll 8
    for (int c = 0; c < GC; ++c) {
        float wx = Wxp[c * J3 + j];
        float wh = Whp[c * J3 + j];
        accx += x_s[c] * wx;
        acch += h_s[c] * wh;
        if (is_c) wch_s[c][jc] = wh;
    }

    const float bj = b[(size_t)pos * J3 + j];
    const float t = accx + bj;

    if (j < GH) {
        // r gate
        float r = 1.f / (1.f + expf(-(t + acch)));
        rh_s[j] = r * h_s[j];
    } else if (j < 2 * GH) {
        // z gate
        float z = 1.f / (1.f + expf(-(t + acch)));
        z_s[j - GH] = z;
    }
    __syncthreads();

    if (is_c) {
        // candidate: (r*h) . Wch  from LDS (64x64, trivial)
        float s = 0.f;
        #pragma unroll 8
        for (int k = 0; k < GH; ++k) s += rh_s[k] * wch_s[k][jc];
        float hc = tanhf(t + s);
        float z = z_s[jc];
        out[(size_t)pos * GH + jc] = (1.f - z) * h_s[jc] + z * hc;
    }
}

extern "C" void kernel_launch(void* const* d_in, const int* in_sizes, int n_in,
                              void* d_out, int out_size, void* d_ws, size_t ws_size,
                              hipStream_t stream) {
    const float* x     = (const float*)d_in[0];
    const float* state = (const float*)d_in[1];
    const float* Wx    = (const float*)d_in[2];
    const float* Wh    = (const float*)d_in[3];
    const float* b     = (const float*)d_in[4];
    float* out = (float*)d_out;

    const int npos = in_sizes[0] / GC;   // B*N = 3312

    gru_cell_kernel<<<npos, 192, 0, stream>>>(x, state, Wx, Wh, b, out);
}

// Round 2
// 338.182 us; speedup vs baseline: 1.0837x; 1.0837x over previous
//
#include <hip/hip_runtime.h>
#include <math.h>

// GRU cell, per-position weights. B=16,N=207,C=64,H=64 -> 3312 positions.
// Memory-bound streaming of Wx+Wh (325 MB total, ~165 MB from HBM after L3).
// v2: float4 weight streaming (4x bytes/load-instr) + LDS partial reduction.

#define GC 64    // input channels
#define GH 64    // hidden
#define J3 192   // 3*H
#define WPP (GC * J3)   // 12288 floats per weight matrix per position

__global__ __launch_bounds__(192) void gru_cell_v2(
    const float* __restrict__ x,      // (P, 64)
    const float* __restrict__ state,  // (P, 64)
    const float* __restrict__ Wx,     // (P, 64, 192)
    const float* __restrict__ Wh,     // (P, 64, 192)
    const float* __restrict__ b,      // (P, 192)
    float* __restrict__ out)          // (P, 64)
{
    const int pos = blockIdx.x;
    const int t = threadIdx.x;        // 0..191
    const int jg = t % 48;            // column group: columns 4*jg .. 4*jg+3
    const int rp = t / 48;            // row phase 0..3 (covers rows rp+4i)

    __shared__ float x_s[GC];
    __shared__ float h_s[GH];
    __shared__ float wch_s[GC * GH];      // staged Wch slice [c*64 + (j-128)], 16 KB
    __shared__ float part[4][J3 + 4];     // partial sums, padded (+4 breaks bank alias)
    __shared__ float rh_s[GH];
    __shared__ float z_s[GH];

    if (t < GC)           x_s[t]      = x[(size_t)pos * GC + t];
    else if (t < GC + GH) h_s[t - GC] = state[(size_t)pos * GH + (t - GC)];
    __syncthreads();

    const float4* __restrict__ Wx4 = (const float4*)(Wx + (size_t)pos * WPP);
    const float4* __restrict__ Wh4 = (const float4*)(Wh + (size_t)pos * WPP);

    float4 acc = {0.f, 0.f, 0.f, 0.f};
    const bool gate = (jg < 32);          // columns < 128 (r,z): need h.Wh summed
    const int wchcol = 4 * (jg - 32);     // for candidate columns: stage Wch

    // Stream both matrices once. Each iteration: 192 threads x float4 = 4 rows.
    #pragma unroll 4
    for (int i = 0; i < 16; ++i) {
        const int c = 4 * i + rp;
        float4 wx4 = Wx4[i * J3 + t];
        float4 wh4 = Wh4[i * J3 + t];
        const float xs = x_s[c];
        acc.x += xs * wx4.x; acc.y += xs * wx4.y;
        acc.z += xs * wx4.z; acc.w += xs * wx4.w;
        if (gate) {
            const float hs = h_s[c];
            acc.x += hs * wh4.x; acc.y += hs * wh4.y;
            acc.z += hs * wh4.z; acc.w += hs * wh4.w;
        } else {
            *((float4*)&wch_s[c * GH + wchcol]) = wh4;
        }
    }

    *((float4*)&part[rp][4 * jg]) = acc;
    __syncthreads();

    // Reduce across the 4 row phases; thread t owns output column t.
    float v = part[0][t] + part[1][t] + part[2][t] + part[3][t]
            + b[(size_t)pos * J3 + t];
    const float tc = v;                   // candidate pre-activation (t >= 128)
    if (t < GH) {
        float r = 1.f / (1.f + expf(-v));
        rh_s[t] = r * h_s[t];
    } else if (t < 2 * GH) {
        z_s[t - GH] = 1.f / (1.f + expf(-v));
    }
    __syncthreads();

    if (t >= 2 * GH) {
        const int jc = t - 2 * GH;
        float s = 0.f;
        #pragma unroll 8
        for (int k = 0; k < GH; ++k) s += rh_s[k] * wch_s[k * GH + jc];
        const float hc = tanhf(tc + s);
        const float z = z_s[jc];
        out[(size_t)pos * GH + jc] = (1.f - z) * h_s[jc] + z * hc;
    }
}

extern "C" void kernel_launch(void* const* d_in, const int* in_sizes, int n_in,
                              void* d_out, int out_size, void* d_ws, size_t ws_size,
                              hipStream_t stream) {
    const float* x     = (const float*)d_in[0];
    const float* state = (const float*)d_in[1];
    const float* Wx    = (const float*)d_in[2];
    const float* Wh    = (const float*)d_in[3];
    const float* b     = (const float*)d_in[4];
    float* out = (float*)d_out;

    const int npos = in_sizes[0] / GC;   // B*N = 3312

    gru_cell_v2<<<npos, 192, 0, stream>>>(x, state, Wx, Wh, b, out);
}